// Round 1
// baseline (688.474 us; speedup 1.0000x reference)
//
#include <hip/hip_runtime.h>
#include <hip/hip_bf16.h>

// ---------------- problem constants ----------------
#define B_SZ   8192
#define XD     362
#define NEXP   3
#define MP     8576   // 67*128 padded-row capacity (max padded total = 8448)

typedef __bf16 bf16x8 __attribute__((ext_vector_type(8)));
typedef float  f32x4  __attribute__((ext_vector_type(4)));

__device__ __forceinline__ unsigned short f2bf(float f) {
    unsigned u = __float_as_uint(f);
    u += 0x7fffu + ((u >> 16) & 1u);
    return (unsigned short)(u >> 16);
}

// ---------------- routing ----------------
// hdr layout (ints): [0..2]=counts, [3..5]=cursors, [6..8]=seg_start,
// [9..11]=padded_count, [16]=float accumulator (as bits)
__global__ void k_init(int* hdr, int* row_of) {
    int gid = blockIdx.x * blockDim.x + threadIdx.x;
    if (gid < MP) row_of[gid] = -1;
    if (gid < 32) hdr[gid] = 0;
}

__global__ void k_count(const int* __restrict__ a, int* hdr) {
    int gid = blockIdx.x * blockDim.x + threadIdx.x;
    if (gid < B_SZ) atomicAdd(&hdr[a[gid]], 1);
}

__global__ void k_offsets(int* hdr) {
    if (blockIdx.x == 0 && threadIdx.x == 0) {
        int off = 0;
        for (int e = 0; e < NEXP; ++e) {
            int c = hdr[e];
            int p = (c + 127) & ~127;
            hdr[6 + e] = off;
            hdr[9 + e] = p;
            off += p;
        }
    }
}

__global__ void k_scatter(const int* __restrict__ a, int* hdr, int* row_of) {
    int gid = blockIdx.x * blockDim.x + threadIdx.x;
    if (gid < B_SZ) {
        int e = a[gid];
        int pos = hdr[6 + e] + atomicAdd(&hdr[3 + e], 1);
        row_of[pos] = gid;
    }
}

// gather x (permuted) -> bf16, K padded 362 -> 384 with zeros; pad rows zeroed
__global__ void k_gather(const float* __restrict__ x, const int* __restrict__ row_of,
                         unsigned short* __restrict__ xg) {
    int r = blockIdx.x;          // 0..MP-1
    int c = threadIdx.x;         // 0..383
    int orig = row_of[r];
    float v = (orig >= 0 && c < XD) ? x[(size_t)orig * XD + c] : 0.f;
    xg[(size_t)r * 384 + c] = f2bf(v);
}

// ---------------- weight transpose+convert: W[e](K,N) f32 -> Wt[e](Np,Kp) bf16 ----------------
__global__ void k_transpose(const float* __restrict__ W, unsigned short* __restrict__ Wt,
                            int K, int N, int Kp, int Np) {
    __shared__ float t[32][33];
    int e  = blockIdx.z;
    int kb = blockIdx.x * 32, nb = blockIdx.y * 32;
    const float* We = W + (size_t)e * K * N;
    unsigned short* Wte = Wt + (size_t)e * Np * Kp;
    int tx = threadIdx.x, ty = threadIdx.y;
#pragma unroll
    for (int j = 0; j < 4; ++j) {
        int k = kb + ty + j * 8, n = nb + tx;
        t[ty + j * 8][tx] = (k < K && n < N) ? We[(size_t)k * N + n] : 0.f;
    }
    __syncthreads();
#pragma unroll
    for (int j = 0; j < 4; ++j) {
        int n = nb + ty + j * 8, k = kb + tx;   // grid covers exactly Np/32 x Kp/32
        Wte[(size_t)n * Kp + k] = f2bf(t[tx][ty + j * 8]);
    }
}

// ---------------- GEMM: C[M,N] = A[M,K] @ Wt^T, per-expert routed tiles ----------------
// 128x128 tile, BK=64, 256 threads = 4 waves in 2x2, each wave 4x4 frags of 16x16x32 MFMA.
template <bool FINAL>
__global__ __launch_bounds__(256) void k_gemm(
    const unsigned short* __restrict__ A, int lda,
    const unsigned short* __restrict__ Bt, int K, int Np,
    const float* __restrict__ bias, int nvalid,
    unsigned short* __restrict__ C, int ldc,
    const int* __restrict__ hdr,
    const float* __restrict__ nextv, const int* __restrict__ row_of,
    float* __restrict__ accum)
{
    __shared__ unsigned short As[128 * 64];
    __shared__ unsigned short Bs[128 * 64];
    __shared__ float red[4];

    int e  = blockIdx.z;
    int mt = blockIdx.y;
    int padded = hdr[9 + e];
    if (mt * 128 >= padded) return;          // block-uniform exit
    int row0 = hdr[6 + e] + mt * 128;
    int n0   = blockIdx.x * 128;

    int tid  = threadIdx.x;
    int wid  = tid >> 6, lane = tid & 63;
    int quad = lane >> 4, l15 = lane & 15;
    int wm = (wid >> 1) * 64, wn = (wid & 1) * 64;

    const unsigned short* Ag = A  + (size_t)row0 * lda;
    const unsigned short* Bg = Bt + (size_t)e * Np * K + (size_t)n0 * K;
    const float* be = bias + (size_t)e * nvalid;

    int srow = lane >> 3;          // 0..7 row within 8-row stage slab
    int scol = (lane & 7) * 8;     // element col (8 bf16 = 16B per lane)

    f32x4 acc[4][4];
#pragma unroll
    for (int i = 0; i < 4; ++i)
#pragma unroll
        for (int j = 0; j < 4; ++j)
            acc[i][j] = (f32x4){0.f, 0.f, 0.f, 0.f};

    for (int k0 = 0; k0 < K; k0 += 64) {
        __syncthreads();   // LDS reuse guard
#pragma unroll
        for (int ii = 0; ii < 4; ++ii) {
            int rbase = wid * 32 + ii * 8;   // wave-uniform
            const unsigned short* gpA = Ag + (size_t)(rbase + srow) * lda + k0 + scol;
            __builtin_amdgcn_global_load_lds(
                (const __attribute__((address_space(1))) void*)gpA,
                (__attribute__((address_space(3))) void*)(As + rbase * 64), 16, 0, 0);
            const unsigned short* gpB = Bg + (size_t)(rbase + srow) * K + k0 + scol;
            __builtin_amdgcn_global_load_lds(
                (const __attribute__((address_space(1))) void*)gpB,
                (__attribute__((address_space(3))) void*)(Bs + rbase * 64), 16, 0, 0);
        }
        __syncthreads();   // compiler drains vmcnt before barrier
#pragma unroll
        for (int kh = 0; kh < 2; ++kh) {
            int kk = kh * 32 + quad * 8;
            bf16x8 af[4], bfr[4];
#pragma unroll
            for (int f = 0; f < 4; ++f)
                af[f] = *(const bf16x8*)(As + (wm + f * 16 + l15) * 64 + kk);
#pragma unroll
            for (int f = 0; f < 4; ++f)
                bfr[f] = *(const bf16x8*)(Bs + (wn + f * 16 + l15) * 64 + kk);
#pragma unroll
            for (int fm = 0; fm < 4; ++fm)
#pragma unroll
                for (int fn = 0; fn < 4; ++fn)
                    acc[fm][fn] = __builtin_amdgcn_mfma_f32_16x16x32_bf16(
                        af[fm], bfr[fn], acc[fm][fn], 0, 0, 0);
        }
    }

    if constexpr (!FINAL) {
        // bias + ReLU, store bf16.  C/D layout: col=lane&15, row=quad*4+i (m89/m91 verified)
#pragma unroll
        for (int fn = 0; fn < 4; ++fn) {
            int n = n0 + wn + fn * 16 + l15;
            float bv = be[n];
#pragma unroll
            for (int fm = 0; fm < 4; ++fm) {
#pragma unroll
                for (int i = 0; i < 4; ++i) {
                    int r = row0 + wm + fm * 16 + quad * 4 + i;
                    float v = acc[fm][fn][i] + bv;
                    v = v > 0.f ? v : 0.f;
                    C[(size_t)r * ldc + n] = f2bf(v);
                }
            }
        }
    } else {
        // fused MSE: (pred - next)^2 for valid rows / n < 362
        float local = 0.f;
#pragma unroll
        for (int fm = 0; fm < 4; ++fm) {
#pragma unroll
            for (int i = 0; i < 4; ++i) {
                int r = row0 + wm + fm * 16 + quad * 4 + i;
                int orig = row_of[r];
                if (orig >= 0) {
                    const float* nrow = nextv + (size_t)orig * XD;
#pragma unroll
                    for (int fn = 0; fn < 4; ++fn) {
                        int n = n0 + wn + fn * 16 + l15;
                        if (n < XD) {
                            float v = acc[fm][fn][i] + be[n];
                            float d = v - nrow[n];
                            local += d * d;
                        }
                    }
                }
            }
        }
        for (int off = 32; off > 0; off >>= 1)
            local += __shfl_down(local, off, 64);
        if (lane == 0) red[wid] = local;
        __syncthreads();
        if (tid == 0) atomicAdd(accum, red[0] + red[1] + red[2] + red[3]);
    }
}

__global__ void k_final(const int* hdr, float* out) {
    if (blockIdx.x == 0 && threadIdx.x == 0) {
        float s = ((const float*)hdr)[16];
        out[0] = s / (float)(B_SZ * XD);
    }
}

// ---------------- host launch ----------------
extern "C" void kernel_launch(void* const* d_in, const int* in_sizes, int n_in,
                              void* d_out, int out_size, void* d_ws, size_t ws_size,
                              hipStream_t stream) {
    const float* x     = (const float*)d_in[0];
    const float* nextv = (const float*)d_in[1];
    const int*   a     = (const int*)d_in[2];
    const float* W0 = (const float*)d_in[3],  *b0 = (const float*)d_in[4];
    const float* W1 = (const float*)d_in[5],  *b1 = (const float*)d_in[6];
    const float* W2 = (const float*)d_in[7],  *b2 = (const float*)d_in[8];
    const float* W3 = (const float*)d_in[9],  *b3 = (const float*)d_in[10];
    const float* W4 = (const float*)d_in[11], *b4 = (const float*)d_in[12];

    int* hdr    = (int*)d_ws;                 // 64 ints
    int* row_of = hdr + 64;                   // MP ints
    unsigned short* xg = (unsigned short*)(row_of + MP);     // MP*384
    unsigned short* hA = xg + (size_t)MP * 384;              // MP*2048
    unsigned short* hB = hA + (size_t)MP * 2048;             // MP*2048
    unsigned short* Wt = hB + (size_t)MP * 2048;             // 3*2048*2048
    float* accum = (float*)(hdr + 16);

    k_init   <<<(MP + 255) / 256, 256, 0, stream>>>(hdr, row_of);
    k_count  <<<(B_SZ + 255) / 256, 256, 0, stream>>>(a, hdr);
    k_offsets<<<1, 64, 0, stream>>>(hdr);
    k_scatter<<<(B_SZ + 255) / 256, 256, 0, stream>>>(a, hdr, row_of);
    k_gather <<<MP, 384, 0, stream>>>(x, row_of, xg);

    // L0: (Mp,384) @ (384,1024)
    k_transpose<<<dim3(12, 32, 3), dim3(32, 8), 0, stream>>>(W0, Wt, XD, 1024, 384, 1024);
    k_gemm<false><<<dim3(8, 64, 3), 256, 0, stream>>>(xg, 384, Wt, 384, 1024, b0, 1024,
                                                      hA, 1024, hdr, nullptr, nullptr, nullptr);
    // L1: (Mp,1024) @ (1024,2048)
    k_transpose<<<dim3(32, 64, 3), dim3(32, 8), 0, stream>>>(W1, Wt, 1024, 2048, 1024, 2048);
    k_gemm<false><<<dim3(16, 64, 3), 256, 0, stream>>>(hA, 1024, Wt, 1024, 2048, b1, 2048,
                                                       hB, 2048, hdr, nullptr, nullptr, nullptr);
    // L2: (Mp,2048) @ (2048,2048)
    k_transpose<<<dim3(64, 64, 3), dim3(32, 8), 0, stream>>>(W2, Wt, 2048, 2048, 2048, 2048);
    k_gemm<false><<<dim3(16, 64, 3), 256, 0, stream>>>(hB, 2048, Wt, 2048, 2048, b2, 2048,
                                                       hA, 2048, hdr, nullptr, nullptr, nullptr);
    // L3: (Mp,2048) @ (2048,1024)
    k_transpose<<<dim3(64, 32, 3), dim3(32, 8), 0, stream>>>(W3, Wt, 2048, 1024, 2048, 1024);
    k_gemm<false><<<dim3(8, 64, 3), 256, 0, stream>>>(hA, 2048, Wt, 2048, 1024, b3, 1024,
                                                      hB, 1024, hdr, nullptr, nullptr, nullptr);
    // L4: (Mp,1024) @ (1024,362->384), fused MSE
    k_transpose<<<dim3(32, 12, 3), dim3(32, 8), 0, stream>>>(W4, Wt, 1024, XD, 1024, 384);
    k_gemm<true><<<dim3(3, 64, 3), 256, 0, stream>>>(hB, 1024, Wt, 1024, 384, b4, XD,
                                                     nullptr, 0, hdr, nextv, row_of, accum);

    k_final<<<1, 64, 0, stream>>>(hdr, (float*)d_out);
}

// Round 2
// 663.265 us; speedup vs baseline: 1.0380x; 1.0380x over previous
//
#include <hip/hip_runtime.h>
#include <hip/hip_bf16.h>

// ---------------- problem constants ----------------
#define B_SZ   8192
#define XD     362
#define NEXP   3
#define NTILES 66          // max padded 128-row tiles across 3 experts
#define MP     (NTILES*128)

typedef __bf16 bf16x8 __attribute__((ext_vector_type(8)));
typedef float  f32x4  __attribute__((ext_vector_type(4)));

__device__ __forceinline__ unsigned short f2bf(float f) {
    unsigned u = __float_as_uint(f);
    u += 0x7fffu + ((u >> 16) & 1u);
    return (unsigned short)(u >> 16);
}

// hdr layout (ints): [0..2]=counts, [3..5]=cursors, [6..8]=seg_start_row,
// [9..11]=padded, [12]=total_tiles, [16]=float accumulator,
// [32..97]=tile->expert table (-1 = inactive)
__global__ void k_init(int* hdr, int* row_of) {
    int gid = blockIdx.x * blockDim.x + threadIdx.x;
    if (gid < MP) row_of[gid] = -1;
    if (gid < 128) hdr[gid] = 0;
}

__global__ void k_count(const int* __restrict__ a, int* hdr) {
    int gid = blockIdx.x * blockDim.x + threadIdx.x;
    if (gid < B_SZ) atomicAdd(&hdr[a[gid]], 1);
}

__global__ void k_offsets(int* hdr) {
    if (blockIdx.x == 0 && threadIdx.x == 0) {
        int off = 0;
        for (int e = 0; e < NEXP; ++e) {
            int c = hdr[e];
            int t = (c + 127) >> 7;
            hdr[6 + e] = off * 128;
            for (int i = 0; i < t; ++i) hdr[32 + off + i] = e;
            off += t;
        }
        hdr[12] = off;
        for (int t2 = off; t2 < NTILES; ++t2) hdr[32 + t2] = -1;
    }
}

__global__ void k_scatter(const int* __restrict__ a, int* hdr, int* row_of) {
    int gid = blockIdx.x * blockDim.x + threadIdx.x;
    if (gid < B_SZ) {
        int e = a[gid];
        int pos = hdr[6 + e] + atomicAdd(&hdr[3 + e], 1);
        row_of[pos] = gid;
    }
}

// gather x (permuted) -> bf16, K padded 362 -> 384 with zeros; pad rows zeroed
__global__ void k_gather(const float* __restrict__ x, const int* __restrict__ row_of,
                         unsigned short* __restrict__ xg) {
    int r = blockIdx.x;
    int c = threadIdx.x;
    int orig = row_of[r];
    float v = (orig >= 0 && c < XD) ? x[(size_t)orig * XD + c] : 0.f;
    xg[(size_t)r * 384 + c] = f2bf(v);
}

// ---------------- weight transpose+convert: W[e](K,N) f32 -> Wt[e](Np,Kp) bf16 ----------------
// 64(K) x 32(N) tiles; stores are 4B (ushort2) coalesced.
__global__ void k_transpose(const float* __restrict__ W, unsigned short* __restrict__ Wt,
                            int K, int N, int Kp, int Np) {
    __shared__ float t[64][33];
    int e  = blockIdx.z;
    int kb = blockIdx.x * 64, nb = blockIdx.y * 32;
    const float* We = W + (size_t)e * K * N;
    unsigned short* Wte = Wt + (size_t)e * Np * Kp;
    int tx = threadIdx.x, ty = threadIdx.y;   // 32 x 8
#pragma unroll
    for (int j = 0; j < 8; ++j) {
        int k = kb + ty + j * 8, n = nb + tx;
        t[ty + j * 8][tx] = (k < K && n < N) ? We[(size_t)k * N + n] : 0.f;
    }
    __syncthreads();
#pragma unroll
    for (int j = 0; j < 4; ++j) {
        int n = ty + j * 8;
        unsigned int lo = f2bf(t[2 * tx][n]);
        unsigned int hi = f2bf(t[2 * tx + 1][n]);
        *(unsigned int*)&Wte[(size_t)(nb + n) * Kp + kb + 2 * tx] = lo | (hi << 16);
    }
}

// ---------------- GEMM: C[M,N] = A[M,K] @ Wt^T, routed 128-row tiles ----------------
// 128x128 tile, BK=64, 4 waves (2x2), each wave 4x4 frags of 16x16x32 MFMA.
// LDS layout XOR-swizzled: 16B col-block c of row r lives at slot (c ^ (r&7)).
template <bool FINAL>
__global__ __launch_bounds__(256) void k_gemm(
    const unsigned short* __restrict__ A, int lda,
    const unsigned short* __restrict__ Bt, int K, int Np,
    const float* __restrict__ bias, int nvalid,
    unsigned short* __restrict__ C, int ldc,
    const int* __restrict__ hdr,
    const float* __restrict__ nextv, const int* __restrict__ row_of,
    float* __restrict__ accum)
{
    __shared__ unsigned short As[128 * 64];
    __shared__ unsigned short Bs[128 * 64];
    __shared__ float red[4];

    int mt = blockIdx.y;
    int e  = hdr[32 + mt];
    if (e < 0) return;                       // block-uniform exit
    int row0 = mt * 128;
    int n0   = blockIdx.x * 128;

    int tid  = threadIdx.x;
    int wid  = tid >> 6, lane = tid & 63;
    int quad = lane >> 4, l15 = lane & 15;
    int sw   = l15 & 7;                      // fragment-read swizzle key (row & 7)
    int wm = (wid >> 1) * 64, wn = (wid & 1) * 64;

    const unsigned short* Ag = A  + (size_t)row0 * lda;
    const unsigned short* Bg = Bt + (size_t)e * Np * K + (size_t)n0 * K;
    const float* be = bias + (size_t)e * nvalid;

    int srow = lane >> 3;                    // row within 8-row stage slab
    int scol = ((lane & 7) ^ srow) * 8;      // swizzled global col (elements)

    f32x4 acc[4][4];
#pragma unroll
    for (int i = 0; i < 4; ++i)
#pragma unroll
        for (int j = 0; j < 4; ++j)
            acc[i][j] = (f32x4){0.f, 0.f, 0.f, 0.f};

    for (int k0 = 0; k0 < K; k0 += 64) {
        __syncthreads();   // LDS reuse guard
#pragma unroll
        for (int ii = 0; ii < 4; ++ii) {
            int rbase = wid * 32 + ii * 8;   // wave-uniform
            const unsigned short* gpA = Ag + (size_t)(rbase + srow) * lda + k0 + scol;
            __builtin_amdgcn_global_load_lds(
                (const __attribute__((address_space(1))) void*)gpA,
                (__attribute__((address_space(3))) void*)(As + rbase * 64), 16, 0, 0);
            const unsigned short* gpB = Bg + (size_t)(rbase + srow) * K + k0 + scol;
            __builtin_amdgcn_global_load_lds(
                (const __attribute__((address_space(1))) void*)gpB,
                (__attribute__((address_space(3))) void*)(Bs + rbase * 64), 16, 0, 0);
        }
        __syncthreads();
#pragma unroll
        for (int kh = 0; kh < 2; ++kh) {
            bf16x8 af[4], bfr[4];
#pragma unroll
            for (int f = 0; f < 4; ++f) {
                int row = wm + f * 16 + l15;
                af[f] = *(const bf16x8*)(As + row * 64 + (((kh * 4 + quad) ^ sw) << 3));
            }
#pragma unroll
            for (int f = 0; f < 4; ++f) {
                int row = wn + f * 16 + l15;
                bfr[f] = *(const bf16x8*)(Bs + row * 64 + (((kh * 4 + quad) ^ sw) << 3));
            }
#pragma unroll
            for (int fm = 0; fm < 4; ++fm)
#pragma unroll
                for (int fn = 0; fn < 4; ++fn)
                    acc[fm][fn] = __builtin_amdgcn_mfma_f32_16x16x32_bf16(
                        af[fm], bfr[fn], acc[fm][fn], 0, 0, 0);
        }
    }

    if constexpr (!FINAL) {
        // bias + ReLU, store bf16.  C/D layout: col=lane&15, row=quad*4+i
#pragma unroll
        for (int fn = 0; fn < 4; ++fn) {
            int n = n0 + wn + fn * 16 + l15;
            float bv = be[n];
#pragma unroll
            for (int fm = 0; fm < 4; ++fm) {
#pragma unroll
                for (int i = 0; i < 4; ++i) {
                    int r = row0 + wm + fm * 16 + quad * 4 + i;
                    float v = acc[fm][fn][i] + bv;
                    v = v > 0.f ? v : 0.f;
                    C[(size_t)r * ldc + n] = f2bf(v);
                }
            }
        }
    } else {
        // fused MSE: (pred - next)^2 for valid rows / n < 362
        float local = 0.f;
#pragma unroll
        for (int fm = 0; fm < 4; ++fm) {
#pragma unroll
            for (int i = 0; i < 4; ++i) {
                int r = row0 + wm + fm * 16 + quad * 4 + i;
                int orig = row_of[r];
                if (orig >= 0) {
                    const float* nrow = nextv + (size_t)orig * XD;
#pragma unroll
                    for (int fn = 0; fn < 4; ++fn) {
                        int n = n0 + wn + fn * 16 + l15;
                        if (n < XD) {
                            float v = acc[fm][fn][i] + be[n];
                            float d = v - nrow[n];
                            local += d * d;
                        }
                    }
                }
            }
        }
        for (int off = 32; off > 0; off >>= 1)
            local += __shfl_down(local, off, 64);
        if (lane == 0) red[wid] = local;
        __syncthreads();
        if (tid == 0) atomicAdd(accum, red[0] + red[1] + red[2] + red[3]);
    }
}

__global__ void k_final(const int* hdr, float* out) {
    if (blockIdx.x == 0 && threadIdx.x == 0) {
        float s = ((const float*)hdr)[16];
        out[0] = s / (float)(B_SZ * XD);
    }
}

// ---------------- host launch ----------------
extern "C" void kernel_launch(void* const* d_in, const int* in_sizes, int n_in,
                              void* d_out, int out_size, void* d_ws, size_t ws_size,
                              hipStream_t stream) {
    const float* x     = (const float*)d_in[0];
    const float* nextv = (const float*)d_in[1];
    const int*   a     = (const int*)d_in[2];
    const float* W0 = (const float*)d_in[3],  *b0 = (const float*)d_in[4];
    const float* W1 = (const float*)d_in[5],  *b1 = (const float*)d_in[6];
    const float* W2 = (const float*)d_in[7],  *b2 = (const float*)d_in[8];
    const float* W3 = (const float*)d_in[9],  *b3 = (const float*)d_in[10];
    const float* W4 = (const float*)d_in[11], *b4 = (const float*)d_in[12];

    int* hdr    = (int*)d_ws;                 // 128 ints
    int* row_of = hdr + 128;                  // MP ints
    unsigned short* xg = (unsigned short*)(row_of + MP);     // MP*384
    unsigned short* hA = xg + (size_t)MP * 384;              // MP*2048
    unsigned short* hB = hA + (size_t)MP * 2048;             // MP*2048
    unsigned short* Wt = hB + (size_t)MP * 2048;             // 3*2048*2048
    float* accum = (float*)(hdr + 16);

    k_init   <<<(MP + 255) / 256, 256, 0, stream>>>(hdr, row_of);
    k_count  <<<(B_SZ + 255) / 256, 256, 0, stream>>>(a, hdr);
    k_offsets<<<1, 64, 0, stream>>>(hdr);
    k_scatter<<<(B_SZ + 255) / 256, 256, 0, stream>>>(a, hdr, row_of);
    k_gather <<<MP, 384, 0, stream>>>(x, row_of, xg);

    // L0: (Mp,384) @ (384,1024)
    k_transpose<<<dim3(6, 32, 3), dim3(32, 8), 0, stream>>>(W0, Wt, XD, 1024, 384, 1024);
    k_gemm<false><<<dim3(8, NTILES), 256, 0, stream>>>(xg, 384, Wt, 384, 1024, b0, 1024,
                                                       hA, 1024, hdr, nullptr, nullptr, nullptr);
    // L1: (Mp,1024) @ (1024,2048)
    k_transpose<<<dim3(16, 64, 3), dim3(32, 8), 0, stream>>>(W1, Wt, 1024, 2048, 1024, 2048);
    k_gemm<false><<<dim3(16, NTILES), 256, 0, stream>>>(hA, 1024, Wt, 1024, 2048, b1, 2048,
                                                        hB, 2048, hdr, nullptr, nullptr, nullptr);
    // L2: (Mp,2048) @ (2048,2048)
    k_transpose<<<dim3(32, 64, 3), dim3(32, 8), 0, stream>>>(W2, Wt, 2048, 2048, 2048, 2048);
    k_gemm<false><<<dim3(16, NTILES), 256, 0, stream>>>(hB, 2048, Wt, 2048, 2048, b2, 2048,
                                                        hA, 2048, hdr, nullptr, nullptr, nullptr);
    // L3: (Mp,2048) @ (2048,1024)
    k_transpose<<<dim3(32, 32, 3), dim3(32, 8), 0, stream>>>(W3, Wt, 2048, 1024, 2048, 1024);
    k_gemm<false><<<dim3(8, NTILES), 256, 0, stream>>>(hA, 2048, Wt, 2048, 1024, b3, 1024,
                                                       hB, 1024, hdr, nullptr, nullptr, nullptr);
    // L4: (Mp,1024) @ (1024,362->384), fused MSE
    k_transpose<<<dim3(16, 12, 3), dim3(32, 8), 0, stream>>>(W4, Wt, 1024, XD, 1024, 384);
    k_gemm<true><<<dim3(3, NTILES), 256, 0, stream>>>(hB, 1024, Wt, 1024, 384, b4, XD,
                                                      nullptr, 0, hdr, nextv, row_of, accum);

    k_final<<<1, 64, 0, stream>>>(hdr, (float*)d_out);
}

// Round 3
// 633.452 us; speedup vs baseline: 1.0869x; 1.0471x over previous
//
#include <hip/hip_runtime.h>
#include <hip/hip_bf16.h>

// ---------------- problem constants ----------------
#define B_SZ   8192
#define XD     362
#define NEXP   3
#define NTILES 66          // max padded 128-row tiles across 3 experts
#define MP     (NTILES*128)

typedef __bf16 bf16x8 __attribute__((ext_vector_type(8)));
typedef float  f32x4  __attribute__((ext_vector_type(4)));

__device__ __forceinline__ unsigned short f2bf(float f) {
    unsigned u = __float_as_uint(f);
    u += 0x7fffu + ((u >> 16) & 1u);
    return (unsigned short)(u >> 16);
}

// hdr layout (ints): [0..2]=counts, [3..5]=cursors, [6..8]=seg_start_row,
// [9..11]=padded, [12]=total_tiles, [16]=float accumulator,
// [32..97]=tile->expert table (-1 = inactive)
__global__ void k_init(int* hdr, int* row_of) {
    int gid = blockIdx.x * blockDim.x + threadIdx.x;
    if (gid < MP) row_of[gid] = -1;
    if (gid < 128) hdr[gid] = 0;
}

__global__ void k_count(const int* __restrict__ a, int* hdr) {
    int gid = blockIdx.x * blockDim.x + threadIdx.x;
    if (gid < B_SZ) atomicAdd(&hdr[a[gid]], 1);
}

__global__ void k_offsets(int* hdr) {
    if (blockIdx.x == 0 && threadIdx.x == 0) {
        int off = 0;
        for (int e = 0; e < NEXP; ++e) {
            int c = hdr[e];
            int t = (c + 127) >> 7;
            hdr[6 + e] = off * 128;
            for (int i = 0; i < t; ++i) hdr[32 + off + i] = e;
            off += t;
        }
        hdr[12] = off;
        for (int t2 = off; t2 < NTILES; ++t2) hdr[32 + t2] = -1;
    }
}

__global__ void k_scatter(const int* __restrict__ a, int* hdr, int* row_of) {
    int gid = blockIdx.x * blockDim.x + threadIdx.x;
    if (gid < B_SZ) {
        int e = a[gid];
        int pos = hdr[6 + e] + atomicAdd(&hdr[3 + e], 1);
        row_of[pos] = gid;
    }
}

// gather x (permuted) -> bf16, K padded 362 -> 384 with zeros; pad rows zeroed
__global__ void k_gather(const float* __restrict__ x, const int* __restrict__ row_of,
                         unsigned short* __restrict__ xg) {
    int r = blockIdx.x;
    int c = threadIdx.x;
    int orig = row_of[r];
    float v = (orig >= 0 && c < XD) ? x[(size_t)orig * XD + c] : 0.f;
    xg[(size_t)r * 384 + c] = f2bf(v);
}

// ---------------- weight transpose+convert: W[e](K,N) f32 -> Wt[e](Np,Kp) bf16 ----------------
__global__ void k_transpose(const float* __restrict__ W, unsigned short* __restrict__ Wt,
                            int K, int N, int Kp, int Np) {
    __shared__ float t[64][33];
    int e  = blockIdx.z;
    int kb = blockIdx.x * 64, nb = blockIdx.y * 32;
    const float* We = W + (size_t)e * K * N;
    unsigned short* Wte = Wt + (size_t)e * Np * Kp;
    int tx = threadIdx.x, ty = threadIdx.y;   // 32 x 8
#pragma unroll
    for (int j = 0; j < 8; ++j) {
        int k = kb + ty + j * 8, n = nb + tx;
        t[ty + j * 8][tx] = (k < K && n < N) ? We[(size_t)k * N + n] : 0.f;
    }
    __syncthreads();
#pragma unroll
    for (int j = 0; j < 4; ++j) {
        int n = ty + j * 8;
        unsigned int lo = f2bf(t[2 * tx][n]);
        unsigned int hi = f2bf(t[2 * tx + 1][n]);
        *(unsigned int*)&Wte[(size_t)(nb + n) * Kp + kb + 2 * tx] = lo | (hi << 16);
    }
}

// ---------------- GEMM: C[M,N] = A[M,K] @ Wt^T, routed 128-row tiles ----------------
// 128x128 tile, BK=64, 4 waves (2x2), each wave 4x4 frags of 16x16x32 MFMA.
// Single-barrier double-buffered pipeline: stage k+1 -> buf[p^1], compute buf[p], barrier.
// LDS XOR-swizzle: 16B col-block c of row r lives at slot (c ^ (r&7)). K%128==0 required.
template <bool FINAL>
__global__ __launch_bounds__(256) void k_gemm(
    const unsigned short* __restrict__ A, int lda,
    const unsigned short* __restrict__ Bt, int K, int Np,
    const float* __restrict__ bias, int nvalid,
    unsigned short* __restrict__ C, int ldc,
    const int* __restrict__ hdr,
    const float* __restrict__ nextv, const int* __restrict__ row_of,
    float* __restrict__ accum)
{
    __shared__ unsigned short As[2][128 * 64];
    __shared__ unsigned short Bs[2][128 * 64];
    __shared__ float red[4];

    int mt = blockIdx.y;
    int e  = hdr[32 + mt];
    if (e < 0) return;                       // block-uniform exit
    int row0 = mt * 128;
    int n0   = blockIdx.x * 128;

    int tid  = threadIdx.x;
    int wid  = tid >> 6, lane = tid & 63;
    int quad = lane >> 4, l15 = lane & 15;
    int sw   = l15 & 7;                      // fragment-read swizzle key (row & 7)
    int wm = (wid >> 1) * 64, wn = (wid & 1) * 64;

    const unsigned short* Ag = A  + (size_t)row0 * lda;
    const unsigned short* Bg = Bt + (size_t)e * Np * K + (size_t)n0 * K;
    const float* be = bias + (size_t)e * nvalid;

    int srow = lane >> 3;                    // row within 8-row stage slab
    int scol = ((lane & 7) ^ srow) * 8;      // swizzled global col (elements)
    int rb0  = wid * 32;                     // wave's staging slab base row

    f32x4 acc[4][4];
#pragma unroll
    for (int i = 0; i < 4; ++i)
#pragma unroll
        for (int j = 0; j < 4; ++j)
            acc[i][j] = (f32x4){0.f, 0.f, 0.f, 0.f};

#define STAGE(K0, P)                                                              \
    {                                                                             \
        _Pragma("unroll")                                                         \
        for (int ii = 0; ii < 4; ++ii) {                                          \
            int rbase = rb0 + ii * 8;                                             \
            const unsigned short* gpA = Ag + (size_t)(rbase + srow) * lda + (K0) + scol; \
            __builtin_amdgcn_global_load_lds(                                     \
                (const __attribute__((address_space(1))) void*)gpA,               \
                (__attribute__((address_space(3))) void*)(As[P] + rbase * 64), 16, 0, 0); \
            const unsigned short* gpB = Bg + (size_t)(rbase + srow) * K + (K0) + scol;   \
            __builtin_amdgcn_global_load_lds(                                     \
                (const __attribute__((address_space(1))) void*)gpB,               \
                (__attribute__((address_space(3))) void*)(Bs[P] + rbase * 64), 16, 0, 0); \
        }                                                                         \
    }

#define COMPUTE(P)                                                                \
    {                                                                             \
        _Pragma("unroll")                                                         \
        for (int kh = 0; kh < 2; ++kh) {                                          \
            bf16x8 af[4], bfr[4];                                                 \
            _Pragma("unroll")                                                     \
            for (int f = 0; f < 4; ++f) {                                         \
                int row = wm + f * 16 + l15;                                      \
                af[f] = *(const bf16x8*)(As[P] + row * 64 + (((kh * 4 + quad) ^ sw) << 3)); \
            }                                                                     \
            _Pragma("unroll")                                                     \
            for (int f = 0; f < 4; ++f) {                                         \
                int row = wn + f * 16 + l15;                                      \
                bfr[f] = *(const bf16x8*)(Bs[P] + row * 64 + (((kh * 4 + quad) ^ sw) << 3)); \
            }                                                                     \
            _Pragma("unroll")                                                     \
            for (int fm = 0; fm < 4; ++fm)                                        \
                _Pragma("unroll")                                                 \
                for (int fn = 0; fn < 4; ++fn)                                    \
                    acc[fm][fn] = __builtin_amdgcn_mfma_f32_16x16x32_bf16(        \
                        af[fm], bfr[fn], acc[fm][fn], 0, 0, 0);                   \
        }                                                                         \
    }

    STAGE(0, 0);
    __syncthreads();                          // drain initial stage
    for (int k0 = 0; k0 < K; k0 += 128) {
        if (k0 + 64 < K) STAGE(k0 + 64, 1);   // prefetch next into buf1
        COMPUTE(0);
        __syncthreads();                      // vmcnt drain is a compute-phase old
        if (k0 + 128 < K) STAGE(k0 + 128, 0); // prefetch next+1 into buf0
        COMPUTE(1);
        __syncthreads();
    }
#undef STAGE
#undef COMPUTE

    if constexpr (!FINAL) {
        // bias + ReLU, store bf16.  C/D layout: col=lane&15, row=quad*4+i
#pragma unroll
        for (int fn = 0; fn < 4; ++fn) {
            int n = n0 + wn + fn * 16 + l15;
            float bv = be[n];
#pragma unroll
            for (int fm = 0; fm < 4; ++fm) {
#pragma unroll
                for (int i = 0; i < 4; ++i) {
                    int r = row0 + wm + fm * 16 + quad * 4 + i;
                    float v = acc[fm][fn][i] + bv;
                    v = v > 0.f ? v : 0.f;
                    C[(size_t)r * ldc + n] = f2bf(v);
                }
            }
        }
    } else {
        // fused MSE: (pred - next)^2 for valid rows / n < 362
        float local = 0.f;
#pragma unroll
        for (int fm = 0; fm < 4; ++fm) {
#pragma unroll
            for (int i = 0; i < 4; ++i) {
                int r = row0 + wm + fm * 16 + quad * 4 + i;
                int orig = row_of[r];
                if (orig >= 0) {
                    const float* nrow = nextv + (size_t)orig * XD;
#pragma unroll
                    for (int fn = 0; fn < 4; ++fn) {
                        int n = n0 + wn + fn * 16 + l15;
                        if (n < XD) {
                            float v = acc[fm][fn][i] + be[n];
                            float d = v - nrow[n];
                            local += d * d;
                        }
                    }
                }
            }
        }
        for (int off = 32; off > 0; off >>= 1)
            local += __shfl_down(local, off, 64);
        if (lane == 0) red[wid] = local;
        __syncthreads();
        if (tid == 0) atomicAdd(accum, red[0] + red[1] + red[2] + red[3]);
    }
}

__global__ void k_final(const int* hdr, float* out) {
    if (blockIdx.x == 0 && threadIdx.x == 0) {
        float s = ((const float*)hdr)[16];
        out[0] = s / (float)(B_SZ * XD);
    }
}

// ---------------- host launch ----------------
extern "C" void kernel_launch(void* const* d_in, const int* in_sizes, int n_in,
                              void* d_out, int out_size, void* d_ws, size_t ws_size,
                              hipStream_t stream) {
    const float* x     = (const float*)d_in[0];
    const float* nextv = (const float*)d_in[1];
    const int*   a     = (const int*)d_in[2];
    const float* W0 = (const float*)d_in[3],  *b0 = (const float*)d_in[4];
    const float* W1 = (const float*)d_in[5],  *b1 = (const float*)d_in[6];
    const float* W2 = (const float*)d_in[7],  *b2 = (const float*)d_in[8];
    const float* W3 = (const float*)d_in[9],  *b3 = (const float*)d_in[10];
    const float* W4 = (const float*)d_in[11], *b4 = (const float*)d_in[12];

    int* hdr    = (int*)d_ws;                 // 128 ints
    int* row_of = hdr + 128;                  // MP ints
    unsigned short* xg = (unsigned short*)(row_of + MP);     // MP*384
    unsigned short* hA = xg + (size_t)MP * 384;              // MP*2048
    unsigned short* hB = hA + (size_t)MP * 2048;             // MP*2048
    unsigned short* Wt = hB + (size_t)MP * 2048;             // 3*2048*2048
    float* accum = (float*)(hdr + 16);

    k_init   <<<(MP + 255) / 256, 256, 0, stream>>>(hdr, row_of);
    k_count  <<<(B_SZ + 255) / 256, 256, 0, stream>>>(a, hdr);
    k_offsets<<<1, 64, 0, stream>>>(hdr);
    k_scatter<<<(B_SZ + 255) / 256, 256, 0, stream>>>(a, hdr, row_of);
    k_gather <<<MP, 384, 0, stream>>>(x, row_of, xg);

    // L0: (Mp,384) @ (384,1024)
    k_transpose<<<dim3(6, 32, 3), dim3(32, 8), 0, stream>>>(W0, Wt, XD, 1024, 384, 1024);
    k_gemm<false><<<dim3(8, NTILES), 256, 0, stream>>>(xg, 384, Wt, 384, 1024, b0, 1024,
                                                       hA, 1024, hdr, nullptr, nullptr, nullptr);
    // L1: (Mp,1024) @ (1024,2048)
    k_transpose<<<dim3(16, 64, 3), dim3(32, 8), 0, stream>>>(W1, Wt, 1024, 2048, 1024, 2048);
    k_gemm<false><<<dim3(16, NTILES), 256, 0, stream>>>(hA, 1024, Wt, 1024, 2048, b1, 2048,
                                                        hB, 2048, hdr, nullptr, nullptr, nullptr);
    // L2: (Mp,2048) @ (2048,2048)
    k_transpose<<<dim3(32, 64, 3), dim3(32, 8), 0, stream>>>(W2, Wt, 2048, 2048, 2048, 2048);
    k_gemm<false><<<dim3(16, NTILES), 256, 0, stream>>>(hB, 2048, Wt, 2048, 2048, b2, 2048,
                                                        hA, 2048, hdr, nullptr, nullptr, nullptr);
    // L3: (Mp,2048) @ (2048,1024)
    k_transpose<<<dim3(32, 32, 3), dim3(32, 8), 0, stream>>>(W3, Wt, 2048, 1024, 2048, 1024);
    k_gemm<false><<<dim3(8, NTILES), 256, 0, stream>>>(hA, 2048, Wt, 2048, 1024, b3, 1024,
                                                       hB, 1024, hdr, nullptr, nullptr, nullptr);
    // L4: (Mp,1024) @ (1024,362->384), fused MSE
    k_transpose<<<dim3(16, 12, 3), dim3(32, 8), 0, stream>>>(W4, Wt, 1024, XD, 1024, 384);
    k_gemm<true><<<dim3(3, NTILES), 256, 0, stream>>>(hB, 1024, Wt, 1024, 384, b4, XD,
                                                      nullptr, 0, hdr, nextv, row_of, accum);

    k_final<<<1, 64, 0, stream>>>(hdr, (float*)d_out);
}

// Round 4
// 537.864 us; speedup vs baseline: 1.2800x; 1.1777x over previous
//
#include <hip/hip_runtime.h>
#include <hip/hip_bf16.h>

// ---------------- problem constants ----------------
#define B_SZ   8192
#define XD     362
#define NEXP   3
#define NTILES 70          // 128-row tile capacity (segments 256-aligned: max 8192+3*255 -> 8960 rows)
#define MP     (NTILES*128)

typedef __bf16 bf16x8 __attribute__((ext_vector_type(8)));
typedef float  f32x4  __attribute__((ext_vector_type(4)));

__device__ __forceinline__ unsigned short f2bf(float f) {
    unsigned u = __float_as_uint(f);
    u += 0x7fffu + ((u >> 16) & 1u);
    return (unsigned short)(u >> 16);
}

// hdr layout (ints): [0..2]=counts, [6..8]=seg_start_row, [12]=total 128-tiles,
// [16]=float accumulator, [32..101]=128-tile -> expert table (-1 = inactive)
// Single-block routing: per-thread counts -> LDS scan -> stable scatter.
// No global atomics (replaces the 8192-atomics-on-3-addresses storm, ~100+us each).
__global__ __launch_bounds__(1024) void k_route(const int* __restrict__ a,
                                                int* __restrict__ hdr,
                                                int* __restrict__ row_of) {
    __shared__ int sc[3][1024];
    int tid = threadIdx.x;
    int ev[8];
    int c0 = 0, c1 = 0, c2 = 0;
#pragma unroll
    for (int j = 0; j < 8; ++j) {
        int e = a[tid * 8 + j];
        ev[j] = e;
        c0 += (e == 0); c1 += (e == 1); c2 += (e == 2);
    }
    sc[0][tid] = c0; sc[1][tid] = c1; sc[2][tid] = c2;
    __syncthreads();
    for (int off = 1; off < 1024; off <<= 1) {   // Hillis-Steele inclusive scan
        int v0 = (tid >= off) ? sc[0][tid - off] : 0;
        int v1 = (tid >= off) ? sc[1][tid - off] : 0;
        int v2 = (tid >= off) ? sc[2][tid - off] : 0;
        __syncthreads();
        sc[0][tid] += v0; sc[1][tid] += v1; sc[2][tid] += v2;
        __syncthreads();
    }
    int tot0 = sc[0][1023], tot1 = sc[1][1023], tot2 = sc[2][1023];
    // pad each segment to 256 rows (2x 128-tiles) so 256-row m-blocks are expert-pure
    int t0 = ((tot0 + 255) >> 8) << 1;
    int t1 = ((tot1 + 255) >> 8) << 1;
    int t2 = ((tot2 + 255) >> 8) << 1;
    int seg0 = 0, seg1 = t0 * 128, seg2 = (t0 + t1) * 128;
    int nt = t0 + t1 + t2;
    int b0 = seg0 + sc[0][tid] - c0;
    int b1 = seg1 + sc[1][tid] - c1;
    int b2 = seg2 + sc[2][tid] - c2;
#pragma unroll
    for (int j = 0; j < 8; ++j) {
        int e = ev[j];
        int pos = (e == 0) ? b0++ : (e == 1) ? b1++ : b2++;
        row_of[pos] = tid * 8 + j;
    }
    if (tid == 0) {
        hdr[0] = tot0; hdr[1] = tot1; hdr[2] = tot2;
        hdr[6] = seg0; hdr[7] = seg1; hdr[8] = seg2;
        hdr[12] = nt;
        hdr[16] = 0;      // zero the f32 loss accumulator
    }
    if (tid < NTILES)
        hdr[32 + tid] = (tid < t0) ? 0 : (tid < t0 + t1) ? 1 : (tid < nt) ? 2 : -1;
    // pad rows (disjoint from valid positions, no barrier needed)
    for (int r = tid; r < MP; r += 1024) {
        int pad;
        if (r < seg1)           pad = (r - seg0) >= tot0;
        else if (r < seg2)      pad = (r - seg1) >= tot1;
        else if (r < nt * 128)  pad = (r - seg2) >= tot2;
        else                    pad = 1;
        if (pad) row_of[r] = -1;
    }
}

// gather x (permuted) -> bf16, K padded 362 -> 384 with zeros; pad rows zeroed
__global__ void k_gather(const float* __restrict__ x, const int* __restrict__ row_of,
                         unsigned short* __restrict__ xg) {
    int r = blockIdx.x;
    int c = threadIdx.x;
    int orig = row_of[r];
    float v = (orig >= 0 && c < XD) ? x[(size_t)orig * XD + c] : 0.f;
    xg[(size_t)r * 384 + c] = f2bf(v);
}

// ---------------- weight transpose+convert: W[e](K,N) f32 -> Wt[e](Np,Kp) bf16 ----------------
__global__ void k_transpose(const float* __restrict__ W, unsigned short* __restrict__ Wt,
                            int K, int N, int Kp, int Np) {
    __shared__ float t[64][33];
    int e  = blockIdx.z;
    int kb = blockIdx.x * 64, nb = blockIdx.y * 32;
    const float* We = W + (size_t)e * K * N;
    unsigned short* Wte = Wt + (size_t)e * Np * Kp;
    int tx = threadIdx.x, ty = threadIdx.y;   // 32 x 8
#pragma unroll
    for (int j = 0; j < 8; ++j) {
        int k = kb + ty + j * 8, n = nb + tx;
        t[ty + j * 8][tx] = (k < K && n < N) ? We[(size_t)k * N + n] : 0.f;
    }
    __syncthreads();
#pragma unroll
    for (int j = 0; j < 4; ++j) {
        int n = ty + j * 8;
        unsigned int lo = f2bf(t[2 * tx][n]);
        unsigned int hi = f2bf(t[2 * tx + 1][n]);
        *(unsigned int*)&Wte[(size_t)(nb + n) * Kp + kb + 2 * tx] = lo | (hi << 16);
    }
}

// ---------------- GEMM: C[M,N] = A[M,K] @ Wt^T, routed m-tiles ----------------
// TM x TN tile, BK=64, WAVES waves each computing a 64x64 sub-tile (4x4 frags of 16x16x32).
// Single-barrier double-buffered pipeline. LDS XOR-swizzle (c ^ (r&7)). K%128==0.
template <int TM, int TN, int WAVES, bool FINAL>
__global__ __launch_bounds__(WAVES * 64) void k_gemm(
    const unsigned short* __restrict__ A, int lda,
    const unsigned short* __restrict__ Bt, int K, int Np,
    const float* __restrict__ bias, int nvalid,
    unsigned short* __restrict__ C, int ldc,
    const int* __restrict__ hdr,
    const float* __restrict__ nextv, const int* __restrict__ row_of,
    float* __restrict__ accum)
{
    __shared__ unsigned short As[2][TM * 64];
    __shared__ unsigned short Bs[2][TN * 64];
    __shared__ float red[WAVES];

    constexpr int WGN = TN / 64;        // waves along n
    constexpr int LA  = TM / (WAVES * 8);  // A staging loads per wave
    constexpr int LB  = TN / (WAVES * 8);  // B staging loads per wave

    int mt = blockIdx.y;
    int e  = hdr[32 + mt * (TM / 128)];  // table is in 128-row units; segments 256-aligned
    if (e < 0) return;                   // block-uniform exit
    int row0 = mt * TM;
    int n0   = blockIdx.x * TN;

    int tid  = threadIdx.x;
    int wid  = tid >> 6, lane = tid & 63;
    int quad = lane >> 4, l15 = lane & 15;
    int sw   = l15 & 7;
    int wm = (wid / WGN) * 64, wn = (wid % WGN) * 64;

    const unsigned short* Ag = A  + (size_t)row0 * lda;
    const unsigned short* Bg = Bt + (size_t)e * Np * K + (size_t)n0 * K;
    const float* be = bias + (size_t)e * nvalid;

    int srow = lane >> 3;
    int scol = ((lane & 7) ^ srow) * 8;

    f32x4 acc[4][4];
#pragma unroll
    for (int i = 0; i < 4; ++i)
#pragma unroll
        for (int j = 0; j < 4; ++j)
            acc[i][j] = (f32x4){0.f, 0.f, 0.f, 0.f};

#define STAGE(K0, P)                                                              \
    {                                                                             \
        _Pragma("unroll")                                                         \
        for (int ii = 0; ii < LA; ++ii) {                                         \
            int rbase = wid * (TM / WAVES) + ii * 8;                              \
            const unsigned short* gp = Ag + (size_t)(rbase + srow) * lda + (K0) + scol; \
            __builtin_amdgcn_global_load_lds(                                     \
                (const __attribute__((address_space(1))) void*)gp,                \
                (__attribute__((address_space(3))) void*)(As[P] + rbase * 64), 16, 0, 0); \
        }                                                                         \
        _Pragma("unroll")                                                         \
        for (int ii = 0; ii < LB; ++ii) {                                         \
            int rbase = wid * (TN / WAVES) + ii * 8;                              \
            const unsigned short* gp = Bg + (size_t)(rbase + srow) * K + (K0) + scol;   \
            __builtin_amdgcn_global_load_lds(                                     \
                (const __attribute__((address_space(1))) void*)gp,                \
                (__attribute__((address_space(3))) void*)(Bs[P] + rbase * 64), 16, 0, 0); \
        }                                                                         \
    }

#define COMPUTE(P)                                                                \
    {                                                                             \
        _Pragma("unroll")                                                         \
        for (int kh = 0; kh < 2; ++kh) {                                          \
            bf16x8 af[4], bfr[4];                                                 \
            _Pragma("unroll")                                                     \
            for (int f = 0; f < 4; ++f) {                                         \
                int row = wm + f * 16 + l15;                                      \
                af[f] = *(const bf16x8*)(As[P] + row * 64 + (((kh * 4 + quad) ^ sw) << 3)); \
            }                                                                     \
            _Pragma("unroll")                                                     \
            for (int f = 0; f < 4; ++f) {                                         \
                int row = wn + f * 16 + l15;                                      \
                bfr[f] = *(const bf16x8*)(Bs[P] + row * 64 + (((kh * 4 + quad) ^ sw) << 3)); \
            }                                                                     \
            _Pragma("unroll")                                                     \
            for (int fm = 0; fm < 4; ++fm)                                        \
                _Pragma("unroll")                                                 \
                for (int fn = 0; fn < 4; ++fn)                                    \
                    acc[fm][fn] = __builtin_amdgcn_mfma_f32_16x16x32_bf16(        \
                        af[fm], bfr[fn], acc[fm][fn], 0, 0, 0);                   \
        }                                                                         \
    }

    STAGE(0, 0);
    __syncthreads();
    for (int k0 = 0; k0 < K; k0 += 128) {
        if (k0 + 64 < K) STAGE(k0 + 64, 1);
        COMPUTE(0);
        __syncthreads();
        if (k0 + 128 < K) STAGE(k0 + 128, 0);
        COMPUTE(1);
        __syncthreads();
    }
#undef STAGE
#undef COMPUTE

    if constexpr (!FINAL) {
#pragma unroll
        for (int fn = 0; fn < 4; ++fn) {
            int n = n0 + wn + fn * 16 + l15;
            float bv = be[n];
#pragma unroll
            for (int fm = 0; fm < 4; ++fm) {
#pragma unroll
                for (int i = 0; i < 4; ++i) {
                    int r = row0 + wm + fm * 16 + quad * 4 + i;
                    float v = acc[fm][fn][i] + bv;
                    v = v > 0.f ? v : 0.f;
                    C[(size_t)r * ldc + n] = f2bf(v);
                }
            }
        }
    } else {
        float local = 0.f;
#pragma unroll
        for (int fm = 0; fm < 4; ++fm) {
#pragma unroll
            for (int i = 0; i < 4; ++i) {
                int r = row0 + wm + fm * 16 + quad * 4 + i;
                int orig = row_of[r];
                if (orig >= 0) {
                    const float* nrow = nextv + (size_t)orig * XD;
#pragma unroll
                    for (int fn = 0; fn < 4; ++fn) {
                        int n = n0 + wn + fn * 16 + l15;
                        if (n < XD) {
                            float v = acc[fm][fn][i] + be[n];
                            float d = v - nrow[n];
                            local += d * d;
                        }
                    }
                }
            }
        }
        for (int off = 32; off > 0; off >>= 1)
            local += __shfl_down(local, off, 64);
        if (lane == 0) red[wid] = local;
        __syncthreads();
        if (tid == 0) {
            float s = 0.f;
#pragma unroll
            for (int w = 0; w < WAVES; ++w) s += red[w];
            atomicAdd(accum, s);
        }
    }
}

__global__ void k_final(const int* hdr, float* out) {
    if (blockIdx.x == 0 && threadIdx.x == 0) {
        float s = ((const float*)hdr)[16];
        out[0] = s / (float)(B_SZ * XD);
    }
}

// ---------------- host launch ----------------
extern "C" void kernel_launch(void* const* d_in, const int* in_sizes, int n_in,
                              void* d_out, int out_size, void* d_ws, size_t ws_size,
                              hipStream_t stream) {
    const float* x     = (const float*)d_in[0];
    const float* nextv = (const float*)d_in[1];
    const int*   a     = (const int*)d_in[2];
    const float* W0 = (const float*)d_in[3],  *b0 = (const float*)d_in[4];
    const float* W1 = (const float*)d_in[5],  *b1 = (const float*)d_in[6];
    const float* W2 = (const float*)d_in[7],  *b2 = (const float*)d_in[8];
    const float* W3 = (const float*)d_in[9],  *b3 = (const float*)d_in[10];
    const float* W4 = (const float*)d_in[11], *b4 = (const float*)d_in[12];

    int* hdr    = (int*)d_ws;                 // 128 ints
    int* row_of = hdr + 128;                  // MP ints
    unsigned short* xg = (unsigned short*)(row_of + MP);     // MP*384
    unsigned short* hA = xg + (size_t)MP * 384;              // MP*2048
    unsigned short* hB = hA + (size_t)MP * 2048;             // MP*2048
    unsigned short* Wt = hB + (size_t)MP * 2048;             // 3*2048*2048
    float* accum = (float*)(hdr + 16);

    k_route <<<1, 1024, 0, stream>>>(a, hdr, row_of);
    k_gather<<<MP, 384, 0, stream>>>(x, row_of, xg);

    // L0: (Mp,384) @ (384,1024)  -- 128x128 tiles
    k_transpose<<<dim3(6, 32, 3), dim3(32, 8), 0, stream>>>(W0, Wt, XD, 1024, 384, 1024);
    k_gemm<128, 128, 4, false><<<dim3(8, NTILES), 256, 0, stream>>>(
        xg, 384, Wt, 384, 1024, b0, 1024, hA, 1024, hdr, nullptr, nullptr, nullptr);
    // L1: (Mp,1024) @ (1024,2048) -- 256x256 tiles
    k_transpose<<<dim3(16, 64, 3), dim3(32, 8), 0, stream>>>(W1, Wt, 1024, 2048, 1024, 2048);
    k_gemm<256, 256, 16, false><<<dim3(8, NTILES / 2), 1024, 0, stream>>>(
        hA, 1024, Wt, 1024, 2048, b1, 2048, hB, 2048, hdr, nullptr, nullptr, nullptr);
    // L2: (Mp,2048) @ (2048,2048) -- 256x256 tiles
    k_transpose<<<dim3(32, 64, 3), dim3(32, 8), 0, stream>>>(W2, Wt, 2048, 2048, 2048, 2048);
    k_gemm<256, 256, 16, false><<<dim3(8, NTILES / 2), 1024, 0, stream>>>(
        hB, 2048, Wt, 2048, 2048, b2, 2048, hA, 2048, hdr, nullptr, nullptr, nullptr);
    // L3: (Mp,2048) @ (2048,1024) -- 256x128 tiles
    k_transpose<<<dim3(32, 32, 3), dim3(32, 8), 0, stream>>>(W3, Wt, 2048, 1024, 2048, 1024);
    k_gemm<256, 128, 8, false><<<dim3(8, NTILES / 2), 512, 0, stream>>>(
        hA, 2048, Wt, 2048, 1024, b3, 1024, hB, 1024, hdr, nullptr, nullptr, nullptr);
    // L4: (Mp,1024) @ (1024,362->384), fused MSE -- 128x128 tiles
    k_transpose<<<dim3(16, 12, 3), dim3(32, 8), 0, stream>>>(W4, Wt, 1024, XD, 1024, 384);
    k_gemm<128, 128, 4, true><<<dim3(3, NTILES), 256, 0, stream>>>(
        hB, 1024, Wt, 1024, 384, b4, XD, nullptr, 0, hdr, nextv, row_of, accum);

    k_final<<<1, 64, 0, stream>>>(hdr, (float*)d_out);
}